// Round 1
// baseline (15376.460 us; speedup 1.0000x reference)
//
#include <hip/hip_runtime.h>
#include <stdint.h>

#define B_  256
#define T_  512
#define I_  256
#define H_  512
#define G3_ 1536

typedef _Float16 half8  __attribute__((ext_vector_type(8)));
typedef _Float16 half4v __attribute__((ext_vector_type(4)));
typedef _Float16 half2v __attribute__((ext_vector_type(2)));
typedef float    float4v __attribute__((ext_vector_type(4)));

__device__ __forceinline__ float sigmoid_f(float x) { return 1.f / (1.f + __expf(-x)); }
__device__ __forceinline__ float tanh_f(float x) {
  x = fminf(15.f, fmaxf(-15.f, x));
  float e = __expf(2.f * x);
  return (e - 1.f) / (e + 1.f);
}

// ---------------------------------------------------------------------------
// Kernel A: igates[t][b][g] = (fp16) sum_k x[b][t][k] * w_ih[g][k] + bias[g]
// 64x64 tile, K=256 in chunks of 64, fp16 MFMA 16x16x32, fp32 accum.
// ---------------------------------------------------------------------------
__global__ __launch_bounds__(256) void igates_gemm(
    const float* __restrict__ x, const float* __restrict__ w_ih,
    const float* __restrict__ bias, _Float16* __restrict__ ig)
{
  __shared__ _Float16 Ash[64][72];   // stride 72 halves: bank-spread for frag reads
  __shared__ _Float16 Bsh[64][72];
  const int tid  = threadIdx.x;
  const int lane = tid & 63;
  const int wv   = tid >> 6;
  const int wm   = wv >> 1, wn = wv & 1;      // 2x2 waves of 32x32
  const int n0   = blockIdx.x * 64;
  const int m0   = blockIdx.y * 64;           // m = t*256 + b

  float4v acc[2][2];
  #pragma unroll
  for (int a = 0; a < 2; ++a)
    #pragma unroll
    for (int c = 0; c < 2; ++c) acc[a][c] = (float4v){0.f, 0.f, 0.f, 0.f};

  for (int kc = 0; kc < I_; kc += 64) {
    #pragma unroll
    for (int i = 0; i < 4; ++i) {           // 1024 float4 loads, 4/thread
      int e   = tid + (i << 8);
      int row = e >> 4;
      int c4  = e & 15;
      int m   = m0 + row;
      int tt  = m >> 8, bb = m & 255;
      float4 va = *(const float4*)(x + ((size_t)bb * T_ + tt) * I_ + kc + (c4 << 2));
      *(half4v*)&Ash[row][c4 << 2] =
          (half4v){(_Float16)va.x, (_Float16)va.y, (_Float16)va.z, (_Float16)va.w};
      float4 vb = *(const float4*)(w_ih + (size_t)(n0 + row) * I_ + kc + (c4 << 2));
      *(half4v*)&Bsh[row][c4 << 2] =
          (half4v){(_Float16)vb.x, (_Float16)vb.y, (_Float16)vb.z, (_Float16)vb.w};
    }
    __syncthreads();
    #pragma unroll
    for (int ks = 0; ks < 2; ++ks) {
      int kk = (ks << 5) + ((lane >> 4) << 3);
      half8 a0 = *(const half8*)&Ash[(wm << 5) + (lane & 15)][kk];
      half8 a1 = *(const half8*)&Ash[(wm << 5) + 16 + (lane & 15)][kk];
      half8 b0 = *(const half8*)&Bsh[(wn << 5) + (lane & 15)][kk];
      half8 b1 = *(const half8*)&Bsh[(wn << 5) + 16 + (lane & 15)][kk];
      acc[0][0] = __builtin_amdgcn_mfma_f32_16x16x32_f16(a0, b0, acc[0][0], 0, 0, 0);
      acc[0][1] = __builtin_amdgcn_mfma_f32_16x16x32_f16(a0, b1, acc[0][1], 0, 0, 0);
      acc[1][0] = __builtin_amdgcn_mfma_f32_16x16x32_f16(a1, b0, acc[1][0], 0, 0, 0);
      acc[1][1] = __builtin_amdgcn_mfma_f32_16x16x32_f16(a1, b1, acc[1][1], 0, 0, 0);
    }
    __syncthreads();
  }
  // epilogue: C/D layout col = lane&15, row = (lane>>4)*4 + r
  #pragma unroll
  for (int mt = 0; mt < 2; ++mt)
    #pragma unroll
    for (int nt = 0; nt < 2; ++nt) {
      int mrow = m0 + (wm << 5) + (mt << 4) + ((lane >> 4) << 2);
      int ncol = n0 + (wn << 5) + (nt << 4) + (lane & 15);
      float bb = bias[ncol];
      #pragma unroll
      for (int r = 0; r < 4; ++r)
        ig[(size_t)(mrow + r) * G3_ + ncol] = (_Float16)(acc[mt][nt][r] + bb);
    }
}

// ---------------------------------------------------------------------------
// Kernel B: persistent GRU scan. 256 WGs = 16 b-groups x 16 col-slices.
// WG (gb,gg): batch rows [16*gb,+16), h-cols [32*gg,+32) (gate cols {j,512+j,1024+j}).
// w_hh fragments live in registers across all 512 steps. h exchanged via global
// double buffer + per-WG monotonic flags (agent scope), sync only within b-group.
// ---------------------------------------------------------------------------
__global__ __launch_bounds__(256) void gru_scan(
    const _Float16* __restrict__ ig, const float* __restrict__ w_hh,
    const float* __restrict__ b_n,
    _Float16* __restrict__ hb0, _Float16* __restrict__ hb1,
    int* flags)
{
  __shared__ _Float16 h_lds[16][520];       // 16 rows x 512 (+8 pad) halves
  __shared__ float partials[4][16][98];     // [wave][b][n] K-split partial sums
  __shared__ float ig_lds[16][96];
  __shared__ float bn_lds[32];

  const int tid  = threadIdx.x;
  const int lane = tid & 63;
  const int wv   = tid >> 6;                 // wave owns K slice [wv*128,+128)
  const int gb   = blockIdx.x & 15;
  const int gg   = blockIdx.x >> 4;
  const int b0   = gb << 4;
  const int j0   = gg << 5;

  // --- load weight fragments once (held in VGPRs for the whole scan) ---
  // B-frag layout: lane holds B[k = (lane>>4)*8 + i][n = lane&15], i.e. w_hh[n_row][k]
  half8 wfrag[6][4];
  #pragma unroll
  for (int nt = 0; nt < 6; ++nt) {
    int gate = nt >> 1;
    int jc   = ((nt & 1) << 4) + (lane & 15);
    const float* wrow = w_hh + (size_t)(gate * H_ + j0 + jc) * H_;
    #pragma unroll
    for (int ks = 0; ks < 4; ++ks) {
      int k = (wv << 7) + (ks << 5) + ((lane >> 4) << 3);
      half8 w;
      #pragma unroll
      for (int i = 0; i < 8; ++i) w[i] = (_Float16)wrow[k + i];
      wfrag[nt][ks] = w;
    }
  }
  if (tid < 32) bn_lds[tid] = b_n[j0 + tid];

  _Float16* bufs[2] = { hb0, hb1 };

  for (int t = 0; t < T_; ++t) {
    // prefetch igates[t] (independent of flags) to overlap with spin-wait
    float igreg[6];
    const _Float16* igsrc = ig + ((size_t)t * B_ + b0) * G3_;
    #pragma unroll
    for (int i = 0; i < 6; ++i) {
      int e = tid + (i << 8);
      int bb = e / 96, c = e - bb * 96;
      int gate = c >> 5, jj = c & 31;
      igreg[i] = (float)igsrc[(size_t)bb * G3_ + gate * H_ + j0 + jj];
    }

    if (t > 0) {
      if (tid < 16) {
        while (__hip_atomic_load(&flags[(tid << 4) | gb],
                                 __ATOMIC_ACQUIRE, __HIP_MEMORY_SCOPE_AGENT) < t)
          __builtin_amdgcn_s_sleep(2);
      }
      __syncthreads();   // also orders wave0's L1-invalidating acquire before all loads
    }

    // stage h(t): 16 x 512 halves from global double buffer
    const _Float16* hsrc = bufs[t & 1] + ((size_t)b0 << 9);
    half8 hreg[4];
    #pragma unroll
    for (int i = 0; i < 4; ++i) {
      int idx = tid + (i << 8);
      int row = idx >> 6, c = idx & 63;
      hreg[i] = *(const half8*)(hsrc + (row << 9) + (c << 3));
    }
    #pragma unroll
    for (int i = 0; i < 4; ++i) {
      int idx = tid + (i << 8);
      int row = idx >> 6, c = idx & 63;
      *(half8*)&h_lds[row][c << 3] = hreg[i];
    }
    #pragma unroll
    for (int i = 0; i < 6; ++i) {
      int e = tid + (i << 8);
      int bb = e / 96, c = e - bb * 96;
      ig_lds[bb][c] = igreg[i];
    }
    __syncthreads();

    // MFMA: each wave does its K=128 slice over 6 column tiles
    float4v acc[6];
    #pragma unroll
    for (int nt = 0; nt < 6; ++nt) acc[nt] = (float4v){0.f, 0.f, 0.f, 0.f};
    #pragma unroll
    for (int ks = 0; ks < 4; ++ks) {
      int k = (wv << 7) + (ks << 5) + ((lane >> 4) << 3);
      half8 a0 = *(const half8*)&h_lds[lane & 15][k];
      #pragma unroll
      for (int nt = 0; nt < 6; ++nt)
        acc[nt] = __builtin_amdgcn_mfma_f32_16x16x32_f16(a0, wfrag[nt][ks], acc[nt], 0, 0, 0);
    }
    #pragma unroll
    for (int nt = 0; nt < 6; ++nt)
      #pragma unroll
      for (int r = 0; r < 4; ++r)
        partials[wv][((lane >> 4) << 2) + r][(nt << 4) + (lane & 15)] = acc[nt][r];
    __syncthreads();

    // epilogue: reduce 4 K-partials, gates, h update. thread -> (b, 2 cols)
    {
      int bb  = tid >> 4;
      int jc0 = (tid & 15) << 1;
      half2v hnew2;
      #pragma unroll
      for (int u = 0; u < 2; ++u) {
        int jc = jc0 + u;
        float hr = partials[0][bb][jc]      + partials[1][bb][jc]
                 + partials[2][bb][jc]      + partials[3][bb][jc];
        float hz = partials[0][bb][32 + jc] + partials[1][bb][32 + jc]
                 + partials[2][bb][32 + jc] + partials[3][bb][32 + jc];
        float hn = partials[0][bb][64 + jc] + partials[1][bb][64 + jc]
                 + partials[2][bb][64 + jc] + partials[3][bb][64 + jc];
        float r  = sigmoid_f(ig_lds[bb][jc] + hr);
        float z  = sigmoid_f(ig_lds[bb][32 + jc] + hz);
        float nv = tanh_f(ig_lds[bb][64 + jc] + r * (hn + bn_lds[jc]));
        float hp = (float)h_lds[bb][j0 + jc];
        hnew2[u] = (_Float16)(nv + z * (hp - nv));
      }
      *(half2v*)(bufs[(t + 1) & 1] + (((size_t)(b0 + bb)) << 9) + j0 + jc0) = hnew2;
    }

    __threadfence();
    __syncthreads();
    if (tid == 0)
      __hip_atomic_store(&flags[blockIdx.x], t + 1,
                         __ATOMIC_RELEASE, __HIP_MEMORY_SCOPE_AGENT);
  }
}

// ---------------------------------------------------------------------------
// Kernel C: e[b] = h_T[b] . w_proj + b_proj   (h_T lives in hb0 since T even)
// ---------------------------------------------------------------------------
__global__ __launch_bounds__(64) void proj_kernel(
    const _Float16* __restrict__ h, const float* __restrict__ w_proj,
    const float* __restrict__ b_proj, float* __restrict__ out)
{
  int b = blockIdx.x;
  int lane = threadIdx.x;
  float s = 0.f;
  #pragma unroll
  for (int i = 0; i < 8; ++i) {
    int j = lane + (i << 6);
    s += (float)h[((size_t)b << 9) + j] * w_proj[j];
  }
  #pragma unroll
  for (int off = 32; off > 0; off >>= 1) s += __shfl_down(s, off, 64);
  if (lane == 0) out[b] = s + b_proj[0];
}

// ---------------------------------------------------------------------------
extern "C" void kernel_launch(void* const* d_in, const int* in_sizes, int n_in,
                              void* d_out, int out_size, void* d_ws, size_t ws_size,
                              hipStream_t stream) {
  const float* x      = (const float*)d_in[0];
  const float* w_ih   = (const float*)d_in[1];
  const float* w_hh   = (const float*)d_in[2];
  const float* bias   = (const float*)d_in[3];
  const float* b_n    = (const float*)d_in[4];
  const float* w_proj = (const float*)d_in[5];
  const float* b_proj = (const float*)d_in[6];
  float* out = (float*)d_out;

  char* ws = (char*)d_ws;
  const size_t IG_BYTES = (size_t)T_ * B_ * G3_ * sizeof(_Float16); // 402,653,184
  const size_t HB_BYTES = (size_t)B_ * H_ * sizeof(_Float16);       // 262,144
  _Float16* ig    = (_Float16*)ws;
  _Float16* hbuf0 = (_Float16*)(ws + IG_BYTES);
  int*      flags = (int*)(ws + IG_BYTES + HB_BYTES);
  _Float16* hbuf1 = (_Float16*)(ws + IG_BYTES + HB_BYTES + 1024);

  // zero h(0) and flags in one async memset (capture-safe)
  hipMemsetAsync(ws + IG_BYTES, 0, HB_BYTES + 1024, stream);

  dim3 gridA(G3_ / 64, (T_ * B_) / 64);   // (24, 2048)
  igates_gemm<<<gridA, 256, 0, stream>>>(x, w_ih, bias, ig);
  gru_scan<<<256, 256, 0, stream>>>(ig, w_hh, b_n, hbuf0, hbuf1, flags);
  proj_kernel<<<B_, 64, 0, stream>>>(hbuf0, w_proj, b_proj, out);
}

// Round 2
// 2177.308 us; speedup vs baseline: 7.0621x; 7.0621x over previous
//
#include <hip/hip_runtime.h>
#include <stdint.h>

#define B_  256
#define T_  512
#define I_  256
#define H_  512
#define G3_ 1536

typedef _Float16 half8  __attribute__((ext_vector_type(8)));
typedef _Float16 half4v __attribute__((ext_vector_type(4)));
typedef float    float4v __attribute__((ext_vector_type(4)));

__device__ __forceinline__ float sigmoid_f(float x) { return 1.f / (1.f + __expf(-x)); }
__device__ __forceinline__ float tanh_f(float x) {
  x = fminf(15.f, fmaxf(-15.f, x));
  float e = __expf(2.f * x);
  return (e - 1.f) / (e + 1.f);
}

// ---------------------------------------------------------------------------
// Kernel A: igates[t][b][g] = (fp16) sum_k x[b][t][k] * w_ih[g][k] + bias[g]
// (unchanged from round 1 — ~4% of total time; scan is the bottleneck)
// ---------------------------------------------------------------------------
__global__ __launch_bounds__(256) void igates_gemm(
    const float* __restrict__ x, const float* __restrict__ w_ih,
    const float* __restrict__ bias, _Float16* __restrict__ ig)
{
  __shared__ _Float16 Ash[64][72];
  __shared__ _Float16 Bsh[64][72];
  const int tid  = threadIdx.x;
  const int lane = tid & 63;
  const int wv   = tid >> 6;
  const int wm   = wv >> 1, wn = wv & 1;
  const int n0   = blockIdx.x * 64;
  const int m0   = blockIdx.y * 64;

  float4v acc[2][2];
  #pragma unroll
  for (int a = 0; a < 2; ++a)
    #pragma unroll
    for (int c = 0; c < 2; ++c) acc[a][c] = (float4v){0.f, 0.f, 0.f, 0.f};

  for (int kc = 0; kc < I_; kc += 64) {
    #pragma unroll
    for (int i = 0; i < 4; ++i) {
      int e   = tid + (i << 8);
      int row = e >> 4;
      int c4  = e & 15;
      int m   = m0 + row;
      int tt  = m >> 8, bb = m & 255;
      float4 va = *(const float4*)(x + ((size_t)bb * T_ + tt) * I_ + kc + (c4 << 2));
      *(half4v*)&Ash[row][c4 << 2] =
          (half4v){(_Float16)va.x, (_Float16)va.y, (_Float16)va.z, (_Float16)va.w};
      float4 vb = *(const float4*)(w_ih + (size_t)(n0 + row) * I_ + kc + (c4 << 2));
      *(half4v*)&Bsh[row][c4 << 2] =
          (half4v){(_Float16)vb.x, (_Float16)vb.y, (_Float16)vb.z, (_Float16)vb.w};
    }
    __syncthreads();
    #pragma unroll
    for (int ks = 0; ks < 2; ++ks) {
      int kk = (ks << 5) + ((lane >> 4) << 3);
      half8 a0 = *(const half8*)&Ash[(wm << 5) + (lane & 15)][kk];
      half8 a1 = *(const half8*)&Ash[(wm << 5) + 16 + (lane & 15)][kk];
      half8 b0 = *(const half8*)&Bsh[(wn << 5) + (lane & 15)][kk];
      half8 b1 = *(const half8*)&Bsh[(wn << 5) + 16 + (lane & 15)][kk];
      acc[0][0] = __builtin_amdgcn_mfma_f32_16x16x32_f16(a0, b0, acc[0][0], 0, 0, 0);
      acc[0][1] = __builtin_amdgcn_mfma_f32_16x16x32_f16(a0, b1, acc[0][1], 0, 0, 0);
      acc[1][0] = __builtin_amdgcn_mfma_f32_16x16x32_f16(a1, b0, acc[1][0], 0, 0, 0);
      acc[1][1] = __builtin_amdgcn_mfma_f32_16x16x32_f16(a1, b1, acc[1][1], 0, 0, 0);
    }
    __syncthreads();
  }
  #pragma unroll
  for (int mt = 0; mt < 2; ++mt)
    #pragma unroll
    for (int nt = 0; nt < 2; ++nt) {
      int mrow = m0 + (wm << 5) + (mt << 4) + ((lane >> 4) << 2);
      int ncol = n0 + (wn << 5) + (nt << 4) + (lane & 15);
      float bb = bias[ncol];
      #pragma unroll
      for (int r = 0; r < 4; ++r)
        ig[(size_t)(mrow + r) * G3_ + ncol] = (_Float16)(acc[mt][nt][r] + bb);
    }
}

// ---------------------------------------------------------------------------
// Kernel B: persistent GRU scan, v2.
// 128 WGs = 16 b-groups x 8 col-slices (64 h-cols each). 256 thr / 4 waves;
// wave owns 16 h-cols x full K=512 -> w_hh fragments = 192 VGPRs/lane, held
// for all 512 steps. Gate epilogue fully in-register (C-layout == ig layout).
//
// Cross-WG h exchange: ALL data+flag traffic uses relaxed agent-scope atomics
// (compile to global_load/store sc1 = read/write-through at the Infinity
// Cache coherence point). No ACQUIRE/RELEASE in the step loop => no
// buffer_inv / buffer_wbl2 cache-maintenance ops (round-1 killer, 28.8us/step).
// Ordering: producers drain own stores with s_waitcnt(0) before the barrier
// that precedes the flag store; consumers' h loads are issued only after the
// flag test and fetch from the coherence point, so stale L1/L2 can't be hit.
// ---------------------------------------------------------------------------
__global__ __launch_bounds__(256, 1) void gru_scan(
    const _Float16* __restrict__ ig, const float* __restrict__ w_hh,
    const float* __restrict__ b_n,
    _Float16* __restrict__ hb0, _Float16* __restrict__ hb1,
    int* flags)
{
  __shared__ _Float16 h_lds[16][520];   // h(t): 16 batches x 512 cols (+8 pad)
  __shared__ _Float16 hn_lds[16][74];   // h(t+1) slice repack for u64 stores

  const int tid   = threadIdx.x;
  const int lane  = tid & 63;
  const int wv    = tid >> 6;                 // wave 0..3
  const int blk   = blockIdx.x;
  // XCD co-location heuristic (blk%8 round-robin): all 8 slices of a b-group
  // share blk&7. Perf-only; correctness is placement-independent.
  const int gb    = ((blk & 7) << 1) | ((blk >> 3) & 1);  // 0..15
  const int gs    = blk >> 4;                              // 0..7
  const int b0    = gb << 4;
  const int j0    = gs << 6;
  const int jw    = j0 + (wv << 4);           // first global h-col of this wave
  const int cn    = lane & 15;
  const int rquad = lane >> 4;                // 0..3

  // --- preload w_hh fragments (held in VGPRs all 512 steps) ---
  // B-frag: lane holds W[jw+cn][k], k = ks*32 + rquad*8 + i
  half8 wfrag[3][16];
  #pragma unroll
  for (int g = 0; g < 3; ++g) {
    const float* wrow = w_hh + (size_t)(g * H_ + jw + cn) * H_;
    #pragma unroll
    for (int ks = 0; ks < 16; ++ks) {
      int k = (ks << 5) + (rquad << 3);
      half8 w;
      #pragma unroll
      for (int i = 0; i < 8; ++i) w[i] = (_Float16)wrow[k + i];
      wfrag[g][ks] = w;
    }
  }
  const float bnv = b_n[jw + cn];

  const int myflag = (gb << 3) | gs;
  _Float16* bufs[2] = { hb0, hb1 };

  for (int t = 0; t < T_; ++t) {
    // ig prefetch in C-layout (independent of peers -> overlaps the spin)
    float igv[3][4];
    {
      const _Float16* igb =
          ig + (size_t)(t * B_ + b0 + (rquad << 2)) * G3_ + jw + cn;
      #pragma unroll
      for (int g = 0; g < 3; ++g)
        #pragma unroll
        for (int r = 0; r < 4; ++r)
          igv[g][r] = (float)igb[(size_t)r * G3_ + g * H_];
    }

    if (t > 0) {
      if (tid < 8) {
        const int* fp = &flags[(gb << 3) | tid];
        while (__hip_atomic_load(fp, __ATOMIC_RELAXED,
                                 __HIP_MEMORY_SCOPE_AGENT) < t)
          __builtin_amdgcn_s_sleep(1);
      }
      __syncthreads();
    }

    // stage h(t) (16 x 512 halves) via relaxed-agent u64 loads (coherent read)
    const _Float16* hsrc = bufs[t & 1] + ((size_t)b0 << 9);
    {
      unsigned long long hv[8];
      #pragma unroll
      for (int i = 0; i < 8; ++i) {
        int idx = (i << 8) + tid;          // 2048 u64 chunks
        int row = idx >> 7, c = idx & 127;
        hv[i] = __hip_atomic_load(
            (const unsigned long long*)(hsrc + ((size_t)row << 9)) + c,
            __ATOMIC_RELAXED, __HIP_MEMORY_SCOPE_AGENT);
      }
      #pragma unroll
      for (int i = 0; i < 8; ++i) {
        int idx = (i << 8) + tid;
        int row = idx >> 7, c = idx & 127;
        *(unsigned long long*)&h_lds[row][c << 2] = hv[i];
      }
    }
    __syncthreads();

    // MFMA: 3 gates x 16 K-chunks, full K=512 per wave
    float4v acc[3];
    acc[0] = (float4v){0.f, 0.f, 0.f, 0.f};
    acc[1] = (float4v){0.f, 0.f, 0.f, 0.f};
    acc[2] = (float4v){0.f, 0.f, 0.f, 0.f};
    #pragma unroll
    for (int ks = 0; ks < 16; ++ks) {
      half8 a = *(const half8*)&h_lds[cn][(ks << 5) + (rquad << 3)];
      acc[0] = __builtin_amdgcn_mfma_f32_16x16x32_f16(a, wfrag[0][ks], acc[0], 0, 0, 0);
      acc[1] = __builtin_amdgcn_mfma_f32_16x16x32_f16(a, wfrag[1][ks], acc[1], 0, 0, 0);
      acc[2] = __builtin_amdgcn_mfma_f32_16x16x32_f16(a, wfrag[2][ks], acc[2], 0, 0, 0);
    }

    // in-register epilogue: lane owns (b = rquad*4+r, col = jw+cn)
    #pragma unroll
    for (int r = 0; r < 4; ++r) {
      float rg = sigmoid_f(igv[0][r] + acc[0][r]);
      float zg = sigmoid_f(igv[1][r] + acc[1][r]);
      float nv = tanh_f(igv[2][r] + rg * (acc[2][r] + bnv));
      float hp = (float)h_lds[(rquad << 2) + r][jw + cn];
      hn_lds[(rquad << 2) + r][(wv << 4) + cn] = (_Float16)(nv + zg * (hp - nv));
    }
    __syncthreads();

    // publish h(t+1) slice: 256 u64 write-through stores
    {
      int row = tid >> 4, c = tid & 15;
      unsigned long long v = *(const unsigned long long*)&hn_lds[row][c << 2];
      __hip_atomic_store(
          (unsigned long long*)(bufs[(t + 1) & 1] + (((size_t)(b0 + row)) << 9) + j0) + c,
          v, __ATOMIC_RELAXED, __HIP_MEMORY_SCOPE_AGENT);
    }
    __builtin_amdgcn_s_waitcnt(0);   // own stores acked at coherence point
    __syncthreads();                 // => all WG stores acked
    if (tid == 0)
      __hip_atomic_store(&flags[myflag], t + 1,
                         __ATOMIC_RELAXED, __HIP_MEMORY_SCOPE_AGENT);
  }
}

// ---------------------------------------------------------------------------
// Kernel C: e[b] = h_T[b] . w_proj + b_proj   (h_T in hb0, T even)
// ---------------------------------------------------------------------------
__global__ __launch_bounds__(64) void proj_kernel(
    const _Float16* __restrict__ h, const float* __restrict__ w_proj,
    const float* __restrict__ b_proj, float* __restrict__ out)
{
  int b = blockIdx.x;
  int lane = threadIdx.x;
  float s = 0.f;
  #pragma unroll
  for (int i = 0; i < 8; ++i) {
    int j = lane + (i << 6);
    s += (float)h[((size_t)b << 9) + j] * w_proj[j];
  }
  #pragma unroll
  for (int off = 32; off > 0; off >>= 1) s += __shfl_down(s, off, 64);
  if (lane == 0) out[b] = s + b_proj[0];
}

// ---------------------------------------------------------------------------
extern "C" void kernel_launch(void* const* d_in, const int* in_sizes, int n_in,
                              void* d_out, int out_size, void* d_ws, size_t ws_size,
                              hipStream_t stream) {
  const float* x      = (const float*)d_in[0];
  const float* w_ih   = (const float*)d_in[1];
  const float* w_hh   = (const float*)d_in[2];
  const float* bias   = (const float*)d_in[3];
  const float* b_n    = (const float*)d_in[4];
  const float* w_proj = (const float*)d_in[5];
  const float* b_proj = (const float*)d_in[6];
  float* out = (float*)d_out;

  char* ws = (char*)d_ws;
  const size_t IG_BYTES = (size_t)T_ * B_ * G3_ * sizeof(_Float16); // 402,653,184
  const size_t HB_BYTES = (size_t)B_ * H_ * sizeof(_Float16);       // 262,144
  _Float16* igbuf = (_Float16*)ws;
  _Float16* hbuf0 = (_Float16*)(ws + IG_BYTES);
  _Float16* hbuf1 = (_Float16*)(ws + IG_BYTES + HB_BYTES);
  int*      flags = (int*)(ws + IG_BYTES + 2 * HB_BYTES);

  // zero h(0), (h1,) flags — capture-safe
  hipMemsetAsync(ws + IG_BYTES, 0, 2 * HB_BYTES + 1024, stream);

  dim3 gridA(G3_ / 64, (T_ * B_) / 64);   // (24, 2048)
  igates_gemm<<<gridA, 256, 0, stream>>>(x, w_ih, bias, igbuf);
  gru_scan<<<128, 256, 0, stream>>>(igbuf, w_hh, b_n, hbuf0, hbuf1, flags);
  proj_kernel<<<B_, 64, 0, stream>>>(hbuf0, w_proj, b_proj, out);
}